// Round 1
// baseline (2776.107 us; speedup 1.0000x reference)
//
#include <hip/hip_runtime.h>
#include <stdint.h>

#define NQ 8192
#define NK 20000
#define RD 512
#define NT 157   // ceil(20000/128)

typedef float f32x4 __attribute__((ext_vector_type(4)));
typedef short s16x8 __attribute__((ext_vector_type(8)));

__device__ __forceinline__ unsigned short bf16_rn(float x) {
    uint32_t u = __float_as_uint(x);
    return (unsigned short)((u + 0x7FFFu + ((u >> 16) & 1)) >> 16);
}

__device__ __forceinline__ void gload_lds16(const unsigned short* g, unsigned short* lds) {
    __builtin_amdgcn_global_load_lds(
        (const __attribute__((address_space(1))) uint32_t*)g,
        (__attribute__((address_space(3))) uint32_t*)lds, 16, 0, 0);
}

// ---------------- preconv: M(fp32) -> Mhi, Mlo (RTZ-hi + RN-residual), MT (RN bf16 of M, transposed) ----
__global__ void preconv_kernel(const float* __restrict__ M,
                               unsigned short* __restrict__ Mhi,
                               unsigned short* __restrict__ Mlo,
                               unsigned short* __restrict__ MT) {
    __shared__ float tilef[64 * 65];
    const int k0 = blockIdx.x * 64, r0 = blockIdx.y * 64;
    const int t = threadIdx.x;
#pragma unroll
    for (int i = 0; i < 16; i++) {
        int e = t + i * 256;
        int kr = e >> 6, cc = e & 63;
        int key = k0 + kr;
        if (key < NK) {
            float x = M[(size_t)key * RD + r0 + cc];
            uint32_t u = __float_as_uint(x);
            Mhi[(size_t)key * RD + r0 + cc] = (unsigned short)(u >> 16);          // RTZ hi
            Mlo[(size_t)key * RD + r0 + cc] = bf16_rn(x - __uint_as_float(u & 0xFFFF0000u));
            tilef[cc * 65 + kr] = x;   // transposed stash
        }
    }
    __syncthreads();
#pragma unroll
    for (int i = 0; i < 16; i++) {
        int e = t + i * 256;
        int rr = e >> 6, kk = e & 63;
        int key = k0 + kk;
        if (key < NK) MT[(size_t)(r0 + rr) * NK + key] = bf16_rn(tilef[rr * 65 + kk]);
    }
}

// ---------------- flash kernel ----------------
// grid 256 blocks x 512 thr (8 waves). Block: 32 query rows. Tile: 128 keys.
// waves: r = w&1 (16-row strip), ch = w>>1 (key/col quarter).
// S = (Qhi+Qlo)x(Khi+Klo) via 3 mfma passes; online softmax; O += P x M (bf16 hi, via MT).
__global__ __launch_bounds__(512, 2) void flash_kernel(
        const float* __restrict__ h,
        const unsigned short* __restrict__ Mhi,
        const unsigned short* __restrict__ Mlo,
        const unsigned short* __restrict__ MT,
        float* __restrict__ out) {
    // frag-linear buffers: frag f = 512 u16 = 64 lanes x 16B, conflict-free
    __shared__ unsigned short skbuf[2][16 * 512];  // S-phase: 8 Khi frags + 8 Klo frags per chunk (1 kstep)
    __shared__ unsigned short ktbuf[2][16 * 512];  // PV: 4 ksteps x 4 col-blocks per chunk
    // aliases into dead skbuf[0] regions (lifetime disjoint from staging, see barriers):
    unsigned short* pbuf = &skbuf[0][0];           // 8 P A-frags (4 kstep x 2 strips) = 8KB
    float* smaxb = (float*)&skbuf[0][4096];        // [2][4][16] rowmax partials
    float* ssumb = smaxb + 128;                    // [2][4][16] sumexp partials

    const int tid = threadIdx.x;
    const int w = tid >> 6, l = tid & 63;
    const int r = w & 1, ch = w >> 1;
    const int l15 = l & 15, q4 = l >> 4;
    const int qbase = blockIdx.x * 32;

    // ---- Q fragments (hi RTZ / lo RN) register-resident ----
    s16x8 qhi[16], qlo[16];
    {
        const float* hrow = h + (size_t)(qbase + r * 16 + l15) * RD;
#pragma unroll
        for (int s = 0; s < 16; s++) {
            const float* src = hrow + s * 32 + q4 * 8;
            f32x4 a = *(const f32x4*)(src);
            f32x4 b = *(const f32x4*)(src + 4);
#pragma unroll
            for (int j = 0; j < 8; j++) {
                float x = (j < 4) ? a[j] : b[j - 4];
                uint32_t u = __float_as_uint(x);
                qhi[s][j] = (short)(u >> 16);
                qlo[s][j] = (short)bf16_rn(x - __uint_as_float(u & 0xFFFF0000u));
            }
        }
    }

    auto stage_s = [&](int tl, int s, unsigned short* buf) {
#pragma unroll
        for (int i = 0; i < 2; i++) {
            int f = w * 2 + i;                 // 0..15: 0-7 = Khi c, 8-15 = Klo c
            int c = f & 7;
            const unsigned short* src = (f < 8) ? Mhi : Mlo;
            int key = tl * 128 + c * 16 + l15;
            gload_lds16(src + (size_t)key * RD + s * 32 + q4 * 8, buf + f * 512);
        }
    };
    auto stage_kt = [&](int tl, int ct, unsigned short* buf) {
#pragma unroll
        for (int i = 0; i < 2; i++) {
            int f = w * 2 + i;                 // f = sk*4 + ci
            int sk = f >> 2, ci = f & 3;
            int rcol = (ct * 4 + ci) * 16 + l15;
            int key = tl * 128 + sk * 32 + q4 * 8;
            gload_lds16(MT + (size_t)rcol * NK + key, buf + f * 512);
        }
    };

    f32x4 O[8];
#pragma unroll
    for (int j = 0; j < 8; j++) O[j] = 0.f;
    float m_run[4], l_run[4];
#pragma unroll
    for (int v = 0; v < 4; v++) { m_run[v] = -3e38f; l_run[v] = 0.f; }

    for (int tile = 0; tile < NT; tile++) {
        // ================= S phase =================
        stage_s(tile, 0, skbuf[0]);
        f32x4 C0 = 0.f, C1 = 0.f;
#pragma unroll
        for (int s = 0; s < 16; s++) {
            __syncthreads();                       // drains stage(s); skbuf[(s+1)&1] free
            if (s < 15) stage_s(tile, s + 1, skbuf[(s + 1) & 1]);
            const unsigned short* buf = skbuf[s & 1];
            {
                int c = ch * 2;
                s16x8 khi = *(const s16x8*)(buf + c * 512 + l * 8);
                s16x8 klo = *(const s16x8*)(buf + (8 + c) * 512 + l * 8);
                C0 = __builtin_amdgcn_mfma_f32_16x16x32_bf16(qhi[s], khi, C0, 0, 0, 0);
                C0 = __builtin_amdgcn_mfma_f32_16x16x32_bf16(qlo[s], khi, C0, 0, 0, 0);
                C0 = __builtin_amdgcn_mfma_f32_16x16x32_bf16(qhi[s], klo, C0, 0, 0, 0);
            }
            {
                int c = ch * 2 + 1;
                s16x8 khi = *(const s16x8*)(buf + c * 512 + l * 8);
                s16x8 klo = *(const s16x8*)(buf + (8 + c) * 512 + l * 8);
                C1 = __builtin_amdgcn_mfma_f32_16x16x32_bf16(qhi[s], khi, C1, 0, 0, 0);
                C1 = __builtin_amdgcn_mfma_f32_16x16x32_bf16(qlo[s], khi, C1, 0, 0, 0);
                C1 = __builtin_amdgcn_mfma_f32_16x16x32_bf16(qhi[s], klo, C1, 0, 0, 0);
            }
        }
        // ================= softmax =================
        if (tile == NT - 1) {                       // mask keys >= NK
            int kg0 = tile * 128 + (ch * 2) * 16 + l15;
            if (kg0 >= NK) C0 = -3e38f;
            if (kg0 + 16 >= NK) C1 = -3e38f;
        }
        f32x4 mx;
#pragma unroll
        for (int v = 0; v < 4; v++) mx[v] = fmaxf(C0[v], C1[v]);
#pragma unroll
        for (int d = 1; d < 16; d <<= 1) {
#pragma unroll
            for (int v = 0; v < 4; v++) mx[v] = fmaxf(mx[v], __shfl_xor(mx[v], d, 16));
        }
        if (l15 == 0) *(f32x4*)&smaxb[(r * 4 + ch) * 16 + q4 * 4] = mx;
        __syncthreads();
        float mnew[4], alpha[4];
#pragma unroll
        for (int v = 0; v < 4; v++) mnew[v] = m_run[v];
#pragma unroll
        for (int cc = 0; cc < 4; cc++) {
            f32x4 tv = *(const f32x4*)&smaxb[(r * 4 + cc) * 16 + q4 * 4];
#pragma unroll
            for (int v = 0; v < 4; v++) mnew[v] = fmaxf(mnew[v], tv[v]);
        }
#pragma unroll
        for (int v = 0; v < 4; v++) { alpha[v] = __expf(m_run[v] - mnew[v]); m_run[v] = mnew[v]; }
        f32x4 ps = 0.f;
#pragma unroll
        for (int cb = 0; cb < 2; cb++) {
            int key_loc = (ch * 2 + cb) * 16 + l15;
            int sk = key_loc >> 5;
            int kq = (key_loc >> 3) & 3;
            int jj = key_loc & 7;
#pragma unroll
            for (int v = 0; v < 4; v++) {
                float sv = (cb == 0) ? C0[v] : C1[v];
                float p = __expf(sv - mnew[v]);
                ps[v] += p;
                int row16 = q4 * 4 + v;
                pbuf[((sk * 2 + r) * 64 + (row16 + 16 * kq)) * 8 + jj] = bf16_rn(p);
            }
        }
#pragma unroll
        for (int d = 1; d < 16; d <<= 1) {
#pragma unroll
            for (int v = 0; v < 4; v++) ps[v] += __shfl_xor(ps[v], d, 16);
        }
        if (l15 == 0) *(f32x4*)&ssumb[(r * 4 + ch) * 16 + q4 * 4] = ps;
        stage_kt(tile, 0, ktbuf[0]);               // prefetch first PV chunk
        __syncthreads();                           // drains stage + P/ssum writes
        // l update + O rescale + P frag load
        f32x4 ts = 0.f;
#pragma unroll
        for (int cc = 0; cc < 4; cc++) ts += *(const f32x4*)&ssumb[(r * 4 + cc) * 16 + q4 * 4];
#pragma unroll
        for (int v = 0; v < 4; v++) l_run[v] = l_run[v] * alpha[v] + ts[v];
#pragma unroll
        for (int j = 0; j < 8; j++) {
#pragma unroll
            for (int v = 0; v < 4; v++) O[j][v] *= alpha[v];
        }
        s16x8 pa[4];
#pragma unroll
        for (int sk = 0; sk < 4; sk++) pa[sk] = *(const s16x8*)(pbuf + ((sk * 2 + r) * 64 + l) * 8);
        // ================= PV phase =================
#pragma unroll
        for (int ct = 0; ct < 8; ct++) {
            if (ct < 7) stage_kt(tile, ct + 1, ktbuf[(ct + 1) & 1]);
            const unsigned short* kb = ktbuf[ct & 1];
#pragma unroll
            for (int sk = 0; sk < 4; sk++) {
                s16x8 bf = *(const s16x8*)(kb + (sk * 4 + ch) * 512 + l * 8);
                O[ct] = __builtin_amdgcn_mfma_f32_16x16x32_bf16(pa[sk], bf, O[ct], 0, 0, 0);
            }
            __syncthreads();
        }
    }
    // ================= epilogue =================
#pragma unroll
    for (int j = 0; j < 8; j++) {
#pragma unroll
        for (int v = 0; v < 4; v++) {
            out[(size_t)(qbase + r * 16 + q4 * 4 + v) * RD + (j * 4 + ch) * 16 + l15] =
                O[j][v] / l_run[v];
        }
    }
}

// ---------------- fallback (ws too small): fp32, slow but exact ----------------
__global__ __launch_bounds__(256) void naive_kernel(const float* __restrict__ h,
                                                    const float* __restrict__ M,
                                                    float* __restrict__ out) {
    __shared__ float hs[16 * 520];
    __shared__ float ms[8 * 520];
    __shared__ float sdot[2][128];
    __shared__ float sm[16], sl[16], sal[16], sp[16][8];
    const int t = threadIdx.x;
    const int qbase = blockIdx.x * 16;
#pragma unroll
    for (int i = 0; i < 32; i++) {
        int e = t + i * 256;
        int row = e >> 9, col = e & 511;
        hs[row * 520 + col] = h[(size_t)(qbase + row) * RD + col];
    }
    if (t < 16) { sm[t] = -3e38f; sl[t] = 0.f; }
    float Oacc[32];
#pragma unroll
    for (int i = 0; i < 32; i++) Oacc[i] = 0.f;
    const int q = t >> 4;
    const int eb = (t & 15) * 32;

    for (int k0 = 0; k0 < NK; k0 += 8) {
        __syncthreads();
#pragma unroll
        for (int i = 0; i < 16; i++) {
            int e = t + i * 256;
            if (e < 4096) {
                int kk = e >> 9, col = e & 511;
                ms[kk * 520 + col] = M[(size_t)(k0 + kk) * RD + col];
            }
        }
        __syncthreads();
        {
            int pair = t & 127, half = t >> 7;
            int qq = pair & 15, kk = pair >> 4;
            const float* hp = &hs[qq * 520 + half * 256];
            const float* mp = &ms[kk * 520 + half * 256];
            float acc = 0.f;
#pragma unroll 8
            for (int e = 0; e < 256; e++) acc += hp[e] * mp[e];
            sdot[half][pair] = acc;
        }
        __syncthreads();
        if (t < 16) {
            int qq = t;
            float s8[8];
#pragma unroll
            for (int kk = 0; kk < 8; kk++) s8[kk] = sdot[0][qq + 16 * kk] + sdot[1][qq + 16 * kk];
            float mn = sm[qq];
#pragma unroll
            for (int kk = 0; kk < 8; kk++) mn = fmaxf(mn, s8[kk]);
            float al = __expf(sm[qq] - mn);
            float addl = 0.f;
#pragma unroll
            for (int kk = 0; kk < 8; kk++) { float p = __expf(s8[kk] - mn); sp[qq][kk] = p; addl += p; }
            sm[qq] = mn; sl[qq] = sl[qq] * al + addl; sal[qq] = al;
        }
        __syncthreads();
        {
            float al = sal[q];
#pragma unroll
            for (int i = 0; i < 32; i++) Oacc[i] *= al;
#pragma unroll
            for (int kk = 0; kk < 8; kk++) {
                float p = sp[q][kk];
                const float* mp = &ms[kk * 520 + eb];
#pragma unroll
                for (int i = 0; i < 32; i++) Oacc[i] += p * mp[i];
            }
        }
    }
    __syncthreads();
    float inv = 1.f / sl[q];
#pragma unroll
    for (int i = 0; i < 32; i++) out[(size_t)(qbase + q) * RD + eb + i] = Oacc[i] * inv;
}

extern "C" void kernel_launch(void* const* d_in, const int* in_sizes, int n_in,
                              void* d_out, int out_size, void* d_ws, size_t ws_size,
                              hipStream_t stream) {
    const float* h = (const float*)d_in[0];
    const float* M = (const float*)d_in[1];
    float* out = (float*)d_out;
    const size_t seg = (size_t)NK * RD;                 // elements per converted buffer
    const size_t need = seg * 2ull * 3ull + 8192ull;    // Mhi+Mlo+MT (u16) + tail-read pad
    if (ws_size >= need) {
        unsigned short* Mhi = (unsigned short*)d_ws;
        unsigned short* Mlo = Mhi + seg;
        unsigned short* MT  = Mlo + seg;
        preconv_kernel<<<dim3(313, 8), 256, 0, stream>>>(M, Mhi, Mlo, MT);
        flash_kernel<<<256, 512, 0, stream>>>(h, Mhi, Mlo, MT, out);
    } else {
        naive_kernel<<<512, 256, 0, stream>>>(h, M, out);
    }
}